// Round 10
// baseline (425.259 us; speedup 1.0000x reference)
//
#include <hip/hip_runtime.h>
#include <cstdint>
#include <cstddef>

#define NUM_USERS 100000
#define NUM_ITEMS 100000
#define NUM_NODES 200000
#define NUM_EDGES 4000000
#define BATCH     4096
#define EMB       64

#define NB    782          // ceil(NUM_NODES / 256) buckets (bucket = row >> 8)
#define CAP   5632         // fixed bucket capacity: mean 5115 + 7.2 sigma
#define CHUNK 16384        // edges per block in k_part1 (245 blocks, runs ~21 records)
#define PTHREADS 1024      // 16 waves/block
#define EPB   16           // CHUNK / PTHREADS edges per thread
#define SIDE_CAP 1048576   // compact side-buffer capacity (records); expected ~245K

// ---------------- bf16 helpers (round-to-nearest-even) ----------------

__device__ __forceinline__ unsigned short f2bf(float f) {
    unsigned u = __float_as_uint(f);
    u = (u + 0x7FFFu + ((u >> 16) & 1u)) >> 16;
    return (unsigned short)u;
}
__device__ __forceinline__ float bf2f(unsigned short b) {
    return __uint_as_float(((unsigned)b) << 16);
}

// ---------------- cvt + binit + gcur-zero + batch-mark (fused housekeeping) ----------

__global__ void k_cvt(const float* __restrict__ uemb, const float* __restrict__ iemb,
                      unsigned short* __restrict__ xb, int* __restrict__ bcur,
                      int* __restrict__ gcur,
                      const int* __restrict__ user, const int* __restrict__ pos,
                      const int* __restrict__ neg, unsigned char* __restrict__ mark) {
    int i = blockIdx.x * blockDim.x + threadIdx.x;
    if (i < NB) bcur[i] = i * CAP;
    if (i == 0) *gcur = 0;
    if (i < BATCH) {
        mark[user[i]] = 1;
        mark[NUM_USERS + pos[i]] = 1;
        mark[NUM_USERS + neg[i]] = 1;
    }
    const int TOT8 = (NUM_NODES * EMB) / 8;                  // 1.6M
    if (i >= TOT8) return;
    size_t off = (size_t)i * 8;
    const size_t UELEMS = (size_t)NUM_USERS * EMB;           // divisible by 8
    const float* src = (off < UELEMS) ? (uemb + off) : (iemb + (off - UELEMS));
    float4 f0 = ((const float4*)src)[0];
    float4 f1 = ((const float4*)src)[1];
    ushort4 o0 = make_ushort4(f2bf(f0.x), f2bf(f0.y), f2bf(f0.z), f2bf(f0.w));
    ushort4 o1 = make_ushort4(f2bf(f1.x), f2bf(f1.y), f2bf(f1.z), f2bf(f1.w));
    ((ushort4*)(xb + off))[0] = o0;
    ((ushort4*)(xb + off))[1] = o1;
}

// ---------------- Pass 1: partition edges into fixed-capacity row-buckets ----------

__global__ void k_part1(const int* __restrict__ erow, const int* __restrict__ ecol,
                        const float* __restrict__ eval_, int* __restrict__ bcur,
                        int2* __restrict__ tmp) {
    __shared__ int hist[NB];
    __shared__ int base[NB];
    int t = threadIdx.x;
    int start = blockIdx.x * CHUNK;
    for (int i = t; i < NB; i += PTHREADS) hist[i] = 0;
    __syncthreads();
    int rows[EPB], ranks[EPB];
#pragma unroll
    for (int k = 0; k < EPB; ++k) {
        int e = start + t + k * PTHREADS;
        if (e < NUM_EDGES) {
            int r = erow[e];
            rows[k]  = r;
            ranks[k] = atomicAdd(&hist[r >> 8], 1);
        } else {
            rows[k] = -1;
        }
    }
    __syncthreads();
    for (int i = t; i < NB; i += PTHREADS) {
        int c = hist[i];
        base[i] = c ? atomicAdd(&bcur[i], c) : 0;
    }
    __syncthreads();
#pragma unroll
    for (int k = 0; k < EPB; ++k) {
        int e = start + t + k * PTHREADS;
        if (rows[k] >= 0) {
            int r   = rows[k];
            int bkt = r >> 8;
            int pos = base[bkt] + ranks[k];
            if (pos < (bkt + 1) * CAP)   // overflow clamp (P ~ 2e-10, deterministic input)
                tmp[pos] = make_int2(((r & 255) << 24) | ecol[e], __float_as_int(eval_[e]));
        }
    }
}

// ---------------- Fused bucket sort + SpMM: h1 = A * x ----------------
// One block per bucket (512 thr, 48 KB LDS -> 3 blocks/CU):
//   1. count per-row (LDS atomics), scan -> local offsets
//   2. scatter bucket records into LDS sorted array (2nd tmp read is L2-hot)
//   3. wave-per-row SpMM from LDS: 4x16-lane edge groups, ushort4 row gathers
//   4. batch-marked rows: copy edges to compact side buffer + row_se for k_final

__global__ void k_bspmm(const int* __restrict__ bcur, const int2* __restrict__ tmp,
                        const unsigned short* __restrict__ xb,
                        unsigned short* __restrict__ h1,
                        const unsigned char* __restrict__ mark,
                        int2* __restrict__ row_se, int2* __restrict__ side,
                        int* __restrict__ gcur) {
    __shared__ int2 srec[CAP];
    __shared__ int cnt[256];
    __shared__ int sc[256];
    __shared__ int loc[256];
    int b = blockIdx.x, t = threadIdx.x;
    int base_row = b << 8;
    int nrows = min(256, NUM_NODES - base_row);
    int s0 = b * CAP;
    int n = min(bcur[b] - s0, CAP);

    if (t < 256) cnt[t] = 0;
    __syncthreads();
    for (int i = t; i < n; i += 512)
        atomicAdd(&cnt[((unsigned)tmp[s0 + i].x) >> 24], 1);
    __syncthreads();
    int v = 0;
    if (t < 256) { v = cnt[t]; sc[t] = v; }
    __syncthreads();
    for (int off = 1; off < 256; off <<= 1) {
        int add = 0;
        if (t < 256 && t >= off) add = sc[t - off];
        __syncthreads();
        if (t < 256 && t >= off) sc[t] += add;
        __syncthreads();
    }
    if (t < 256) loc[t] = sc[t] - v;   // exclusive local offset
    __syncthreads();
    for (int i = t; i < n; i += 512) {
        int2 rec = tmp[s0 + i];
        int pos = atomicAdd(&loc[((unsigned)rec.x) >> 24], 1);
        srec[pos] = rec;
    }
    __syncthreads();

    int w = t >> 6, lane = t & 63;
    int g = lane >> 4, q = (lane & 15) * 4;
    for (int k = 0; k < 32; ++k) {
        int r = w + (k << 3);
        if (r >= nrows) break;
        int end = loc[r], start = end - cnt[r];
        float a0 = 0.f, a1 = 0.f, a2 = 0.f, a3 = 0.f;
        for (int e = start; e < end; e += 8) {
            int iA = e + g, iB = e + 4 + g;
            int2 pA = srec[iA < end ? iA : start];
            int2 pB = srec[iB < end ? iB : start];
            float vA = (iA < end) ? __int_as_float(pA.y) : 0.f;
            float vB = (iB < end) ? __int_as_float(pB.y) : 0.f;
            int cA = pA.x & 0xFFFFFF, cB = pB.x & 0xFFFFFF;
            ushort4 xA = *(const ushort4*)(xb + (size_t)cA * EMB + q);
            ushort4 xB = *(const ushort4*)(xb + (size_t)cB * EMB + q);
            a0 = fmaf(vA, bf2f(xA.x), a0); a1 = fmaf(vA, bf2f(xA.y), a1);
            a2 = fmaf(vA, bf2f(xA.z), a2); a3 = fmaf(vA, bf2f(xA.w), a3);
            a0 = fmaf(vB, bf2f(xB.x), a0); a1 = fmaf(vB, bf2f(xB.y), a1);
            a2 = fmaf(vB, bf2f(xB.z), a2); a3 = fmaf(vB, bf2f(xB.w), a3);
        }
        a0 += __shfl_xor(a0, 16, 64); a1 += __shfl_xor(a1, 16, 64);
        a2 += __shfl_xor(a2, 16, 64); a3 += __shfl_xor(a3, 16, 64);
        a0 += __shfl_xor(a0, 32, 64); a1 += __shfl_xor(a1, 32, 64);
        a2 += __shfl_xor(a2, 32, 64); a3 += __shfl_xor(a3, 32, 64);
        if (lane < 16) {
            ushort4 o = make_ushort4(f2bf(a0), f2bf(a1), f2bf(a2), f2bf(a3));
            *(ushort4*)(h1 + (size_t)(base_row + r) * EMB + q) = o;
        }
        if (mark[base_row + r]) {
            int rcnt = end - start;
            int p = 0;
            if (lane == 0) p = atomicAdd(gcur, rcnt);
            p = __shfl(p, 0, 64);
            if (lane == 0)
                row_se[base_row + r] = make_int2(p, (p + rcnt <= SIDE_CAP) ? rcnt : 0);
            if (p + rcnt <= SIDE_CAP)
                for (int i2 = lane; i2 < rcnt; i2 += 64) side[p + i2] = srec[start + i2];
        }
    }
}

// ---------------- Fused layer 2 + scoring (compact side-buffer edges) ----------------

__device__ __forceinline__ const float* node_ptr(int c, const float* __restrict__ uemb,
                                                 const float* __restrict__ iemb) {
    return (c < NUM_USERS) ? (uemb + (size_t)c * EMB)
                           : (iemb + (size_t)(c - NUM_USERS) * EMB);
}

__global__ void k_final(const int* __restrict__ user, const int* __restrict__ pos,
                        const int* __restrict__ neg,
                        const int2* __restrict__ row_se, const int2* __restrict__ side,
                        const float* __restrict__ uemb, const float* __restrict__ iemb,
                        const unsigned short* __restrict__ h1, float* __restrict__ out) {
    __shared__ float lds[3 * EMB];
    int b    = blockIdx.x;
    int w    = threadIdx.x >> 6;
    int lane = threadIdx.x & 63;
    int g = lane >> 4;
    int q = (lane & 15) * 4;

    int node;
    if (w == 0)      node = user[b];
    else if (w == 1) node = NUM_USERS + pos[b];
    else             node = NUM_USERS + neg[b];

    int2 se = row_se[node];
    int p = se.x, cn = se.y;
    float a0 = 0.f, a1 = 0.f, a2 = 0.f, a3 = 0.f;
    for (int e = 0; e < cn; e += 8) {
        int iA = e + g, iB = e + 4 + g;
        int2 pA = side[p + (iA < cn ? iA : 0)];
        int2 pB = side[p + (iB < cn ? iB : 0)];
        float vA = (iA < cn) ? __int_as_float(pA.y) : 0.f;
        float vB = (iB < cn) ? __int_as_float(pB.y) : 0.f;
        int cA = pA.x & 0xFFFFFF, cB = pB.x & 0xFFFFFF;
        ushort4 yA = *(const ushort4*)(h1 + (size_t)cA * EMB + q);
        ushort4 yB = *(const ushort4*)(h1 + (size_t)cB * EMB + q);
        a0 = fmaf(vA, bf2f(yA.x), a0); a1 = fmaf(vA, bf2f(yA.y), a1);
        a2 = fmaf(vA, bf2f(yA.z), a2); a3 = fmaf(vA, bf2f(yA.w), a3);
        a0 = fmaf(vB, bf2f(yB.x), a0); a1 = fmaf(vB, bf2f(yB.y), a1);
        a2 = fmaf(vB, bf2f(yB.z), a2); a3 = fmaf(vB, bf2f(yB.w), a3);
    }
    a0 += __shfl_xor(a0, 16, 64); a1 += __shfl_xor(a1, 16, 64);
    a2 += __shfl_xor(a2, 16, 64); a3 += __shfl_xor(a3, 16, 64);
    a0 += __shfl_xor(a0, 32, 64); a1 += __shfl_xor(a1, 32, 64);
    a2 += __shfl_xor(a2, 32, 64); a3 += __shfl_xor(a3, 32, 64);

    if (lane < 16) {
        const float* xbp = node_ptr(node, uemb, iemb) + q;
        float4  xd = *(const float4*)xbp;
        ushort4 hn = *(const ushort4*)(h1 + (size_t)node * EMB + q);
        a0 = (a0 + xd.x + bf2f(hn.x)) / 3.0f;
        a1 = (a1 + xd.y + bf2f(hn.y)) / 3.0f;
        a2 = (a2 + xd.z + bf2f(hn.z)) / 3.0f;
        a3 = (a3 + xd.w + bf2f(hn.w)) / 3.0f;
        *(float4*)(lds + w * EMB + q) = make_float4(a0, a1, a2, a3);
    }
    __syncthreads();

    if (w < 2) {
        float prod = lds[lane] * lds[(w + 1) * EMB + lane];
        for (int off = 32; off; off >>= 1) prod += __shfl_xor(prod, off, 64);
        if (lane == 0) out[w * BATCH + b] = prod;
    }
}

// ---------------- launch ----------------

extern "C" void kernel_launch(void* const* d_in, const int* in_sizes, int n_in,
                              void* d_out, int out_size, void* d_ws, size_t ws_size,
                              hipStream_t stream) {
    const int*   user  = (const int*)d_in[0];
    const int*   pos   = (const int*)d_in[1];
    const int*   neg   = (const int*)d_in[2];
    const int*   erow  = (const int*)d_in[3];
    const int*   ecol  = (const int*)d_in[4];
    const float* eval_ = (const float*)d_in[5];
    const float* uemb  = (const float*)d_in[6];
    const float* iemb  = (const float*)d_in[7];
    float* out = (float*)d_out;

    char* ws = (char*)d_ws;
    // layout (bytes):
    //   xb      : 0          .. 25,600,000   (200000*64 bf16)
    //   h1      : 25,600,000 .. 51,200,000   (bf16)
    //   tmp     : 51,200,000 .. 86,433,792   (782*5632 int2 records)
    //   row_se  : 86,433,792 .. 88,033,792   (200000 int2)
    //   bcur    : 88,033,792 .. +4,096
    //   gcur    : 88,037,888 .. +4,096
    //   mark    : 88,041,984 .. +200,704     (200000 bytes)
    //   side    : 88,242,688 .. 96,631,296   (1M int2; expected use ~245K)
    unsigned short* xb = (unsigned short*)(ws);
    unsigned short* h1 = (unsigned short*)(ws + 25600000);
    int2* tmp     = (int2*)(ws + 51200000);
    int2* row_se  = (int2*)(ws + 86433792);
    int*  bcur    = (int*)(ws + 88033792);
    int*  gcur    = (int*)(ws + 88037888);
    unsigned char* mark = (unsigned char*)(ws + 88041984);
    int2* side    = (int2*)(ws + 88242688);

    hipMemsetAsync(mark, 0, NUM_NODES, stream);

    k_cvt<<<((NUM_NODES * EMB) / 8 + 255) / 256, 256, 0, stream>>>(
        uemb, iemb, xb, bcur, gcur, user, pos, neg, mark);

    k_part1<<<(NUM_EDGES + CHUNK - 1) / CHUNK, PTHREADS, 0, stream>>>(erow, ecol, eval_,
                                                                      bcur, tmp);

    k_bspmm<<<NB, 512, 0, stream>>>(bcur, tmp, xb, h1, mark, row_se, side, gcur);

    k_final<<<BATCH, 192, 0, stream>>>(user, pos, neg, row_se, side,
                                       uemb, iemb, h1, out);
}

// Round 11
// 396.718 us; speedup vs baseline: 1.0719x; 1.0719x over previous
//
#include <hip/hip_runtime.h>
#include <cstdint>
#include <cstddef>

#define NUM_USERS 100000
#define NUM_ITEMS 100000
#define NUM_NODES 200000
#define NUM_EDGES 4000000
#define BATCH     4096
#define EMB       64

#define RPB   196          // rows per bucket
#define NB    1021         // ceil(NUM_NODES / RPB) buckets -> 1021 blocks, 4/CU = single round
#define CAP   4368         // records per bucket region: mean 3918 + ~7.2 sigma
#define CHUNK 16384        // edges per block in k_part1
#define PTHREADS 1024
#define EPB   16           // CHUNK / PTHREADS
#define SIDE_CAP 1048576   // compact side-buffer capacity (records); expected ~245K

// ---------------- bf16 helpers (round-to-nearest-even) ----------------

__device__ __forceinline__ unsigned short f2bf(float f) {
    unsigned u = __float_as_uint(f);
    u = (u + 0x7FFFu + ((u >> 16) & 1u)) >> 16;
    return (unsigned short)u;
}
__device__ __forceinline__ float bf2f(unsigned short b) {
    return __uint_as_float(((unsigned)b) << 16);
}

// ---------------- cvt + binit + gcur-zero + batch-mark (fused housekeeping) ----------

__global__ void k_cvt(const float* __restrict__ uemb, const float* __restrict__ iemb,
                      unsigned short* __restrict__ xb, int* __restrict__ bcur,
                      int* __restrict__ gcur,
                      const int* __restrict__ user, const int* __restrict__ pos,
                      const int* __restrict__ neg, unsigned char* __restrict__ mark) {
    int i = blockIdx.x * blockDim.x + threadIdx.x;
    if (i < NB) bcur[i] = i * CAP;
    if (i == 0) *gcur = 0;
    if (i < BATCH) {
        mark[user[i]] = 1;
        mark[NUM_USERS + pos[i]] = 1;
        mark[NUM_USERS + neg[i]] = 1;
    }
    const int TOT8 = (NUM_NODES * EMB) / 8;                  // 1.6M
    if (i >= TOT8) return;
    size_t off = (size_t)i * 8;
    const size_t UELEMS = (size_t)NUM_USERS * EMB;           // divisible by 8
    const float* src = (off < UELEMS) ? (uemb + off) : (iemb + (off - UELEMS));
    float4 f0 = ((const float4*)src)[0];
    float4 f1 = ((const float4*)src)[1];
    ushort4 o0 = make_ushort4(f2bf(f0.x), f2bf(f0.y), f2bf(f0.z), f2bf(f0.w));
    ushort4 o1 = make_ushort4(f2bf(f1.x), f2bf(f1.y), f2bf(f1.z), f2bf(f1.w));
    ((ushort4*)(xb + off))[0] = o0;
    ((ushort4*)(xb + off))[1] = o1;
}

// ---------------- Pass 1: partition edges into fixed-capacity row-buckets ----------

__global__ void k_part1(const int* __restrict__ erow, const int* __restrict__ ecol,
                        const float* __restrict__ eval_, int* __restrict__ bcur,
                        int2* __restrict__ tmp) {
    __shared__ int hist[NB];
    __shared__ int base[NB];
    int t = threadIdx.x;
    int start = blockIdx.x * CHUNK;
    for (int i = t; i < NB; i += PTHREADS) hist[i] = 0;
    __syncthreads();
    int rows[EPB], ranks[EPB];
#pragma unroll
    for (int k = 0; k < EPB; ++k) {
        int e = start + t + k * PTHREADS;
        if (e < NUM_EDGES) {
            int r = erow[e];
            rows[k]  = r;
            ranks[k] = atomicAdd(&hist[r / RPB], 1);
        } else {
            rows[k] = -1;
        }
    }
    __syncthreads();
    for (int i = t; i < NB; i += PTHREADS) {
        int c = hist[i];
        base[i] = c ? atomicAdd(&bcur[i], c) : 0;
    }
    __syncthreads();
#pragma unroll
    for (int k = 0; k < EPB; ++k) {
        int e = start + t + k * PTHREADS;
        if (rows[k] >= 0) {
            int r   = rows[k];
            int bkt = r / RPB;
            int pos = base[bkt] + ranks[k];
            if (pos < (bkt + 1) * CAP)   // overflow clamp (P ~ 1e-9, deterministic input)
                tmp[pos] = make_int2(((r - bkt * RPB) << 24) | ecol[e],
                                     __float_as_int(eval_[e]));
        }
    }
}

// ---------------- Fused bucket sort + SpMM: h1 = A * x ----------------
// One block per 196-row bucket (512 thr, ~38 KB LDS -> 4 blocks/CU, 1021 blocks
// <= 1024 resident slots -> SINGLE scheduling round, no quantization tail):
//   1. count per-row (LDS atomics), scan -> local offsets
//   2. scatter bucket records into LDS-sorted srec (2nd tmp read is L2-hot)
//   3. wave-per-row SpMM from LDS: 4x16-lane edge groups, ushort4 row gathers
//   4. batch-marked rows: copy edges to compact side buffer + row_se for k_final

__global__ __launch_bounds__(512, 8)
void k_bspmm(const int* __restrict__ bcur, const int2* __restrict__ tmp,
             const unsigned short* __restrict__ xb,
             unsigned short* __restrict__ h1,
             const unsigned char* __restrict__ mark,
             int2* __restrict__ row_se, int2* __restrict__ side,
             int* __restrict__ gcur) {
    __shared__ int2 srec[CAP];
    __shared__ int cnt[256];
    __shared__ int sc[256];
    __shared__ int loc[256];
    int b = blockIdx.x, t = threadIdx.x;
    int base_row = b * RPB;
    int nrows = min(RPB, NUM_NODES - base_row);
    int s0 = b * CAP;
    int n = min(bcur[b] - s0, CAP);

    if (t < 256) cnt[t] = 0;
    __syncthreads();
    for (int i = t; i < n; i += 512)
        atomicAdd(&cnt[((unsigned)tmp[s0 + i].x) >> 24], 1);
    __syncthreads();
    int v = 0;
    if (t < 256) { v = cnt[t]; sc[t] = v; }
    __syncthreads();
    for (int off = 1; off < 256; off <<= 1) {
        int add = 0;
        if (t < 256 && t >= off) add = sc[t - off];
        __syncthreads();
        if (t < 256 && t >= off) sc[t] += add;
        __syncthreads();
    }
    if (t < 256) loc[t] = sc[t] - v;   // exclusive local offset
    __syncthreads();
    for (int i = t; i < n; i += 512) {
        int2 rec = tmp[s0 + i];
        int pos = atomicAdd(&loc[((unsigned)rec.x) >> 24], 1);
        srec[pos] = rec;
    }
    __syncthreads();

    int w = t >> 6, lane = t & 63;
    int g = lane >> 4, q = (lane & 15) * 4;
    for (int r = w; r < nrows; r += 8) {
        int end = loc[r], start = end - cnt[r];
        float a0 = 0.f, a1 = 0.f, a2 = 0.f, a3 = 0.f;
        for (int e = start; e < end; e += 8) {
            int iA = e + g, iB = e + 4 + g;
            int2 pA = srec[iA < end ? iA : start];
            int2 pB = srec[iB < end ? iB : start];
            float vA = (iA < end) ? __int_as_float(pA.y) : 0.f;
            float vB = (iB < end) ? __int_as_float(pB.y) : 0.f;
            int cA = pA.x & 0xFFFFFF, cB = pB.x & 0xFFFFFF;
            ushort4 xA = *(const ushort4*)(xb + (size_t)cA * EMB + q);
            ushort4 xB = *(const ushort4*)(xb + (size_t)cB * EMB + q);
            a0 = fmaf(vA, bf2f(xA.x), a0); a1 = fmaf(vA, bf2f(xA.y), a1);
            a2 = fmaf(vA, bf2f(xA.z), a2); a3 = fmaf(vA, bf2f(xA.w), a3);
            a0 = fmaf(vB, bf2f(xB.x), a0); a1 = fmaf(vB, bf2f(xB.y), a1);
            a2 = fmaf(vB, bf2f(xB.z), a2); a3 = fmaf(vB, bf2f(xB.w), a3);
        }
        a0 += __shfl_xor(a0, 16, 64); a1 += __shfl_xor(a1, 16, 64);
        a2 += __shfl_xor(a2, 16, 64); a3 += __shfl_xor(a3, 16, 64);
        a0 += __shfl_xor(a0, 32, 64); a1 += __shfl_xor(a1, 32, 64);
        a2 += __shfl_xor(a2, 32, 64); a3 += __shfl_xor(a3, 32, 64);
        if (lane < 16) {
            ushort4 o = make_ushort4(f2bf(a0), f2bf(a1), f2bf(a2), f2bf(a3));
            *(ushort4*)(h1 + (size_t)(base_row + r) * EMB + q) = o;
        }
        if (mark[base_row + r]) {
            int rcnt = end - start;
            int p = 0;
            if (lane == 0) p = atomicAdd(gcur, rcnt);
            p = __shfl(p, 0, 64);
            if (lane == 0)
                row_se[base_row + r] = make_int2(p, (p + rcnt <= SIDE_CAP) ? rcnt : 0);
            if (p + rcnt <= SIDE_CAP)
                for (int i2 = lane; i2 < rcnt; i2 += 64) side[p + i2] = srec[start + i2];
        }
    }
}

// ---------------- Fused layer 2 + scoring (compact side-buffer edges) ----------------

__device__ __forceinline__ const float* node_ptr(int c, const float* __restrict__ uemb,
                                                 const float* __restrict__ iemb) {
    return (c < NUM_USERS) ? (uemb + (size_t)c * EMB)
                           : (iemb + (size_t)(c - NUM_USERS) * EMB);
}

__global__ void k_final(const int* __restrict__ user, const int* __restrict__ pos,
                        const int* __restrict__ neg,
                        const int2* __restrict__ row_se, const int2* __restrict__ side,
                        const float* __restrict__ uemb, const float* __restrict__ iemb,
                        const unsigned short* __restrict__ h1, float* __restrict__ out) {
    __shared__ float lds[3 * EMB];
    int b    = blockIdx.x;
    int w    = threadIdx.x >> 6;
    int lane = threadIdx.x & 63;
    int g = lane >> 4;
    int q = (lane & 15) * 4;

    int node;
    if (w == 0)      node = user[b];
    else if (w == 1) node = NUM_USERS + pos[b];
    else             node = NUM_USERS + neg[b];

    int2 se = row_se[node];
    int p = se.x, cn = se.y;
    float a0 = 0.f, a1 = 0.f, a2 = 0.f, a3 = 0.f;
    for (int e = 0; e < cn; e += 8) {
        int iA = e + g, iB = e + 4 + g;
        int2 pA = side[p + (iA < cn ? iA : 0)];
        int2 pB = side[p + (iB < cn ? iB : 0)];
        float vA = (iA < cn) ? __int_as_float(pA.y) : 0.f;
        float vB = (iB < cn) ? __int_as_float(pB.y) : 0.f;
        int cA = pA.x & 0xFFFFFF, cB = pB.x & 0xFFFFFF;
        ushort4 yA = *(const ushort4*)(h1 + (size_t)cA * EMB + q);
        ushort4 yB = *(const ushort4*)(h1 + (size_t)cB * EMB + q);
        a0 = fmaf(vA, bf2f(yA.x), a0); a1 = fmaf(vA, bf2f(yA.y), a1);
        a2 = fmaf(vA, bf2f(yA.z), a2); a3 = fmaf(vA, bf2f(yA.w), a3);
        a0 = fmaf(vB, bf2f(yB.x), a0); a1 = fmaf(vB, bf2f(yB.y), a1);
        a2 = fmaf(vB, bf2f(yB.z), a2); a3 = fmaf(vB, bf2f(yB.w), a3);
    }
    a0 += __shfl_xor(a0, 16, 64); a1 += __shfl_xor(a1, 16, 64);
    a2 += __shfl_xor(a2, 16, 64); a3 += __shfl_xor(a3, 16, 64);
    a0 += __shfl_xor(a0, 32, 64); a1 += __shfl_xor(a1, 32, 64);
    a2 += __shfl_xor(a2, 32, 64); a3 += __shfl_xor(a3, 32, 64);

    if (lane < 16) {
        const float* xbp = node_ptr(node, uemb, iemb) + q;
        float4  xd = *(const float4*)xbp;
        ushort4 hn = *(const ushort4*)(h1 + (size_t)node * EMB + q);
        a0 = (a0 + xd.x + bf2f(hn.x)) / 3.0f;
        a1 = (a1 + xd.y + bf2f(hn.y)) / 3.0f;
        a2 = (a2 + xd.z + bf2f(hn.z)) / 3.0f;
        a3 = (a3 + xd.w + bf2f(hn.w)) / 3.0f;
        *(float4*)(lds + w * EMB + q) = make_float4(a0, a1, a2, a3);
    }
    __syncthreads();

    if (w < 2) {
        float prod = lds[lane] * lds[(w + 1) * EMB + lane];
        for (int off = 32; off; off >>= 1) prod += __shfl_xor(prod, off, 64);
        if (lane == 0) out[w * BATCH + b] = prod;
    }
}

// ---------------- launch ----------------

extern "C" void kernel_launch(void* const* d_in, const int* in_sizes, int n_in,
                              void* d_out, int out_size, void* d_ws, size_t ws_size,
                              hipStream_t stream) {
    const int*   user  = (const int*)d_in[0];
    const int*   pos   = (const int*)d_in[1];
    const int*   neg   = (const int*)d_in[2];
    const int*   erow  = (const int*)d_in[3];
    const int*   ecol  = (const int*)d_in[4];
    const float* eval_ = (const float*)d_in[5];
    const float* uemb  = (const float*)d_in[6];
    const float* iemb  = (const float*)d_in[7];
    float* out = (float*)d_out;

    char* ws = (char*)d_ws;
    // layout (bytes):
    //   xb      : 0          .. 25,600,000   (200000*64 bf16)
    //   h1      : 25,600,000 .. 51,200,000   (bf16)
    //   tmp     : 51,200,000 .. 86,877,824   (1021*4368 int2 records)
    //   row_se  : 86,877,824 .. 88,477,824   (200000 int2)
    //   bcur    : 88,477,824 .. +4,096
    //   gcur    : 88,481,920 .. +4,096
    //   mark    : 88,486,016 .. +200,704     (200000 bytes)
    //   side    : 88,686,720 .. 97,075,328   (1M int2; expected use ~245K)
    unsigned short* xb = (unsigned short*)(ws);
    unsigned short* h1 = (unsigned short*)(ws + 25600000);
    int2* tmp     = (int2*)(ws + 51200000);
    int2* row_se  = (int2*)(ws + 86877824);
    int*  bcur    = (int*)(ws + 88477824);
    int*  gcur    = (int*)(ws + 88481920);
    unsigned char* mark = (unsigned char*)(ws + 88486016);
    int2* side    = (int2*)(ws + 88686720);

    hipMemsetAsync(mark, 0, NUM_NODES, stream);

    k_cvt<<<((NUM_NODES * EMB) / 8 + 255) / 256, 256, 0, stream>>>(
        uemb, iemb, xb, bcur, gcur, user, pos, neg, mark);

    k_part1<<<(NUM_EDGES + CHUNK - 1) / CHUNK, PTHREADS, 0, stream>>>(erow, ecol, eval_,
                                                                      bcur, tmp);

    k_bspmm<<<NB, 512, 0, stream>>>(bcur, tmp, xb, h1, mark, row_se, side, gcur);

    k_final<<<BATCH, 192, 0, stream>>>(user, pos, neg, row_se, side,
                                       uemb, iemb, h1, out);
}

// Round 12
// 343.003 us; speedup vs baseline: 1.2398x; 1.1566x over previous
//
#include <hip/hip_runtime.h>
#include <cstdint>
#include <cstddef>

#define NUM_USERS 100000
#define NUM_ITEMS 100000
#define NUM_NODES 200000
#define NUM_EDGES 4000000
#define BATCH     4096
#define EMB       64

#define NB    782          // ceil(NUM_NODES / 256) buckets (bucket = row >> 8)
#define CAP   5632         // fixed bucket capacity: mean 5115 + 7.2 sigma
#define CHUNK 16384        // edges per block in k_part1 (245 blocks, runs ~21 records)
#define PTHREADS 1024
#define EPB   16           // CHUNK / PTHREADS

// ---------------- bf16 helpers (round-to-nearest-even) ----------------

__device__ __forceinline__ unsigned short f2bf(float f) {
    unsigned u = __float_as_uint(f);
    u = (u + 0x7FFFu + ((u >> 16) & 1u)) >> 16;
    return (unsigned short)u;
}
__device__ __forceinline__ float bf2f(unsigned short b) {
    return __uint_as_float(((unsigned)b) << 16);
}

// ---------------- cvt + bucket-cursor init (fused housekeeping) ----------------

__global__ void k_cvt(const float* __restrict__ uemb, const float* __restrict__ iemb,
                      unsigned short* __restrict__ xb, int* __restrict__ bcur) {
    int i = blockIdx.x * blockDim.x + threadIdx.x;
    if (i < NB) bcur[i] = i * CAP;
    const int TOT8 = (NUM_NODES * EMB) / 8;                  // 1.6M
    if (i >= TOT8) return;
    size_t off = (size_t)i * 8;
    const size_t UELEMS = (size_t)NUM_USERS * EMB;           // divisible by 8
    const float* src = (off < UELEMS) ? (uemb + off) : (iemb + (off - UELEMS));
    float4 f0 = ((const float4*)src)[0];
    float4 f1 = ((const float4*)src)[1];
    ushort4 o0 = make_ushort4(f2bf(f0.x), f2bf(f0.y), f2bf(f0.z), f2bf(f0.w));
    ushort4 o1 = make_ushort4(f2bf(f1.x), f2bf(f1.y), f2bf(f1.z), f2bf(f1.w));
    ((ushort4*)(xb + off))[0] = o0;
    ((ushort4*)(xb + off))[1] = o1;
}

// ---------------- Pass 1: partition edges into fixed-capacity row-buckets ----------

__global__ void k_part1(const int* __restrict__ erow, const int* __restrict__ ecol,
                        const float* __restrict__ eval_, int* __restrict__ bcur,
                        int2* __restrict__ tmp) {
    __shared__ int hist[NB];
    __shared__ int base[NB];
    int t = threadIdx.x;
    int start = blockIdx.x * CHUNK;
    for (int i = t; i < NB; i += PTHREADS) hist[i] = 0;
    __syncthreads();
    int rows[EPB], ranks[EPB];
#pragma unroll
    for (int k = 0; k < EPB; ++k) {
        int e = start + t + k * PTHREADS;
        if (e < NUM_EDGES) {
            int r = erow[e];
            rows[k]  = r;
            ranks[k] = atomicAdd(&hist[r >> 8], 1);
        } else {
            rows[k] = -1;
        }
    }
    __syncthreads();
    for (int i = t; i < NB; i += PTHREADS) {
        int c = hist[i];
        base[i] = c ? atomicAdd(&bcur[i], c) : 0;
    }
    __syncthreads();
#pragma unroll
    for (int k = 0; k < EPB; ++k) {
        int e = start + t + k * PTHREADS;
        if (rows[k] >= 0) {
            int r   = rows[k];
            int bkt = r >> 8;
            int pos = base[bkt] + ranks[k];
            if (pos < (bkt + 1) * CAP)   // overflow clamp (P ~ 2e-10, deterministic input)
                tmp[pos] = make_int2(((r & 255) << 24) | ecol[e], __float_as_int(eval_[e]));
        }
    }
}

// ---------------- Pass 2: per-bucket sort -> FIXED-CAP epack + rowext ----------------
// One block per bucket, 512 threads. Output positions are bucket-local
// (b*CAP + local scan), so no global prefix scan (k_bscan) is needed.
// rowext[node] = (start, count) of the node's records in epack.

__global__ void k_part2(const int* __restrict__ bcur, const int2* __restrict__ tmp,
                        int2* __restrict__ epack, int2* __restrict__ rowext) {
    __shared__ int cnt[256];
    __shared__ int sc[256];
    __shared__ int loc[256];
    int b = blockIdx.x, t = threadIdx.x;
    int base_row = b << 8;
    int nrows = min(256, NUM_NODES - base_row);
    int s0 = b * CAP;
    int n = min(bcur[b] - s0, CAP);
    if (t < 256) cnt[t] = 0;
    __syncthreads();
    for (int i = t; i < n; i += 512)
        atomicAdd(&cnt[((unsigned)tmp[s0 + i].x) >> 24], 1);
    __syncthreads();
    int v = 0;
    if (t < 256) { v = cnt[t]; sc[t] = v; }
    __syncthreads();
    for (int off = 1; off < 256; off <<= 1) {
        int add = 0;
        if (t < 256 && t >= off) add = sc[t - off];
        __syncthreads();
        if (t < 256 && t >= off) sc[t] += add;
        __syncthreads();
    }
    if (t < 256) {
        int cur = s0 + sc[t] - v;   // exclusive, bucket-local
        if (t < nrows) rowext[base_row + t] = make_int2(cur, v);
        loc[t] = cur;
    }
    __syncthreads();
    for (int i = t; i < n; i += 512) {
        int2 rec = tmp[s0 + i];
        int pos = atomicAdd(&loc[((unsigned)rec.x) >> 24], 1);
        epack[pos] = make_int2(rec.x & 0xFFFFFF, rec.y);
    }
}

// ---------------- SpMM layer 1: h1 = A * x ----------------
// Wave = 1 row. Four 16-lane edge-groups: group g handles edge e+g, lane
// holds dim-quad (lane&15)*4 via one ushort4 (8 B) load -> one wave-level
// VMEM issue covers 4 edges (512 B). Cross-group sum via 2 shfl_xor.

__global__ void k_spmm1(const int2* __restrict__ rowext, const int2* __restrict__ epack,
                        const unsigned short* __restrict__ xb,
                        unsigned short* __restrict__ h1) {
    int wid  = (blockIdx.x * blockDim.x + threadIdx.x) >> 6;
    int lane = threadIdx.x & 63;
    if (wid >= NUM_NODES) return;
    int g = lane >> 4;
    int q = (lane & 15) * 4;
    int2 se = rowext[wid];
    int s = se.x, t = se.x + se.y;
    float a0 = 0.f, a1 = 0.f, a2 = 0.f, a3 = 0.f;
    for (int e = s; e < t; e += 8) {
        int eA = e + g, eB = e + 4 + g;
        int2 pA = epack[eA < t ? eA : s];
        int2 pB = epack[eB < t ? eB : s];
        float vA = (eA < t) ? __int_as_float(pA.y) : 0.f;
        float vB = (eB < t) ? __int_as_float(pB.y) : 0.f;
        ushort4 xA = *(const ushort4*)(xb + (size_t)pA.x * EMB + q);
        ushort4 xB = *(const ushort4*)(xb + (size_t)pB.x * EMB + q);
        a0 = fmaf(vA, bf2f(xA.x), a0); a1 = fmaf(vA, bf2f(xA.y), a1);
        a2 = fmaf(vA, bf2f(xA.z), a2); a3 = fmaf(vA, bf2f(xA.w), a3);
        a0 = fmaf(vB, bf2f(xB.x), a0); a1 = fmaf(vB, bf2f(xB.y), a1);
        a2 = fmaf(vB, bf2f(xB.z), a2); a3 = fmaf(vB, bf2f(xB.w), a3);
    }
    a0 += __shfl_xor(a0, 16, 64); a1 += __shfl_xor(a1, 16, 64);
    a2 += __shfl_xor(a2, 16, 64); a3 += __shfl_xor(a3, 16, 64);
    a0 += __shfl_xor(a0, 32, 64); a1 += __shfl_xor(a1, 32, 64);
    a2 += __shfl_xor(a2, 32, 64); a3 += __shfl_xor(a3, 32, 64);
    if (lane < 16) {
        ushort4 o = make_ushort4(f2bf(a0), f2bf(a1), f2bf(a2), f2bf(a3));
        *(ushort4*)(h1 + (size_t)wid * EMB + q) = o;
    }
}

// ---------------- Fused layer 2 + scoring (same 4-edge-group gather) ----------------

__device__ __forceinline__ const float* node_ptr(int c, const float* __restrict__ uemb,
                                                 const float* __restrict__ iemb) {
    return (c < NUM_USERS) ? (uemb + (size_t)c * EMB)
                           : (iemb + (size_t)(c - NUM_USERS) * EMB);
}

__global__ void k_final(const int* __restrict__ user, const int* __restrict__ pos,
                        const int* __restrict__ neg,
                        const int2* __restrict__ rowext, const int2* __restrict__ epack,
                        const float* __restrict__ uemb, const float* __restrict__ iemb,
                        const unsigned short* __restrict__ h1, float* __restrict__ out) {
    __shared__ float lds[3 * EMB];
    int b    = blockIdx.x;
    int w    = threadIdx.x >> 6;
    int lane = threadIdx.x & 63;
    int g = lane >> 4;
    int q = (lane & 15) * 4;

    int node;
    if (w == 0)      node = user[b];
    else if (w == 1) node = NUM_USERS + pos[b];
    else             node = NUM_USERS + neg[b];

    int2 se = rowext[node];
    int s = se.x, t = se.x + se.y;
    float a0 = 0.f, a1 = 0.f, a2 = 0.f, a3 = 0.f;
    for (int e = s; e < t; e += 8) {
        int eA = e + g, eB = e + 4 + g;
        int2 pA = epack[eA < t ? eA : s];
        int2 pB = epack[eB < t ? eB : s];
        float vA = (eA < t) ? __int_as_float(pA.y) : 0.f;
        float vB = (eB < t) ? __int_as_float(pB.y) : 0.f;
        ushort4 yA = *(const ushort4*)(h1 + (size_t)pA.x * EMB + q);
        ushort4 yB = *(const ushort4*)(h1 + (size_t)pB.x * EMB + q);
        a0 = fmaf(vA, bf2f(yA.x), a0); a1 = fmaf(vA, bf2f(yA.y), a1);
        a2 = fmaf(vA, bf2f(yA.z), a2); a3 = fmaf(vA, bf2f(yA.w), a3);
        a0 = fmaf(vB, bf2f(yB.x), a0); a1 = fmaf(vB, bf2f(yB.y), a1);
        a2 = fmaf(vB, bf2f(yB.z), a2); a3 = fmaf(vB, bf2f(yB.w), a3);
    }
    a0 += __shfl_xor(a0, 16, 64); a1 += __shfl_xor(a1, 16, 64);
    a2 += __shfl_xor(a2, 16, 64); a3 += __shfl_xor(a3, 16, 64);
    a0 += __shfl_xor(a0, 32, 64); a1 += __shfl_xor(a1, 32, 64);
    a2 += __shfl_xor(a2, 32, 64); a3 += __shfl_xor(a3, 32, 64);

    if (lane < 16) {
        const float* xbp = node_ptr(node, uemb, iemb) + q;
        float4  xd = *(const float4*)xbp;
        ushort4 hn = *(const ushort4*)(h1 + (size_t)node * EMB + q);
        a0 = (a0 + xd.x + bf2f(hn.x)) / 3.0f;
        a1 = (a1 + xd.y + bf2f(hn.y)) / 3.0f;
        a2 = (a2 + xd.z + bf2f(hn.z)) / 3.0f;
        a3 = (a3 + xd.w + bf2f(hn.w)) / 3.0f;
        *(float4*)(lds + w * EMB + q) = make_float4(a0, a1, a2, a3);
    }
    __syncthreads();

    if (w < 2) {
        float prod = lds[lane] * lds[(w + 1) * EMB + lane];
        for (int off = 32; off; off >>= 1) prod += __shfl_xor(prod, off, 64);
        if (lane == 0) out[w * BATCH + b] = prod;
    }
}

// ---------------- launch ----------------

extern "C" void kernel_launch(void* const* d_in, const int* in_sizes, int n_in,
                              void* d_out, int out_size, void* d_ws, size_t ws_size,
                              hipStream_t stream) {
    const int*   user  = (const int*)d_in[0];
    const int*   pos   = (const int*)d_in[1];
    const int*   neg   = (const int*)d_in[2];
    const int*   erow  = (const int*)d_in[3];
    const int*   ecol  = (const int*)d_in[4];
    const float* eval_ = (const float*)d_in[5];
    const float* uemb  = (const float*)d_in[6];
    const float* iemb  = (const float*)d_in[7];
    float* out = (float*)d_out;

    char* ws = (char*)d_ws;
    // layout (bytes) — tmp ALIASES h1 (tmp dead before spmm1 writes h1, stream-ordered):
    //   xb      : 0          .. 25,600,000   (200000*64 bf16)
    //   h1      : 25,600,000 .. 51,200,000   (bf16)
    //   tmp     : 25,600,000 .. 60,833,792   (782*5632 int2, aliases h1)
    //   rowext  : 60,833,792 .. 62,433,792   (200000 int2)
    //   bcur    : 62,433,792 .. 62,437,888
    //   epack   : 62,437,888 .. 97,671,680   (782*5632 int2, fixed-CAP regions)
    unsigned short* xb = (unsigned short*)(ws);
    unsigned short* h1 = (unsigned short*)(ws + 25600000);
    int2* tmp     = (int2*)(ws + 25600000);
    int2* rowext  = (int2*)(ws + 60833792);
    int*  bcur    = (int*)(ws + 62433792);
    int2* epack   = (int2*)(ws + 62437888);

    k_cvt<<<((NUM_NODES * EMB) / 8 + 255) / 256, 256, 0, stream>>>(uemb, iemb, xb, bcur);

    k_part1<<<(NUM_EDGES + CHUNK - 1) / CHUNK, PTHREADS, 0, stream>>>(erow, ecol, eval_,
                                                                      bcur, tmp);

    k_part2<<<NB, 512, 0, stream>>>(bcur, tmp, epack, rowext);

    k_spmm1<<<(NUM_NODES * 64 + 255) / 256, 256, 0, stream>>>(rowext, epack, xb, h1);

    k_final<<<BATCH, 192, 0, stream>>>(user, pos, neg, rowext, epack,
                                       uemb, iemb, h1, out);
}